// Round 1
// baseline (96.878 us; speedup 1.0000x reference)
//
#include <hip/hip_runtime.h>
#include <hip/hip_bf16.h>

// EntityRepr: gather spans -> mention means -> entity means + mask.
// B=32, L=512, H=768, E=32, M=8, S=4.
// Outputs concatenated fp32: entity [B,E,H] | mentions [B,E,M,H] | mask [B,E,M].

#define B_  32
#define L_  512
#define H_  768
#define E_  32
#define M_  8
#define S_  4
#define H4_ (H_ / 4)              // 192 float4 per vector

#define ENT_ELEMS   (B_ * E_ * H_)          // 786432
#define MEN_ELEMS   (B_ * E_ * M_ * H_)     // 6291456
#define MEN_OFFSET  ENT_ELEMS               // 786432
#define MASK_OFFSET (ENT_ELEMS + MEN_ELEMS) // 7077888

__global__ __launch_bounds__(H4_) void entity_repr_kernel(
    const float* __restrict__ tok,   // [B, L, H]
    const int*   __restrict__ idx,   // [B, E, M, S]
    float*       __restrict__ out)
{
    const int be = blockIdx.x;            // b*E + e, 0..1023
    const int b  = be >> 5;               // /E_ (E_=32)
    const int t  = threadIdx.x;           // 0..191, one float4 column

    const float4* tb = (const float4*)(tok) + (size_t)b * L_ * H4_;
    const int*    ip = idx + (size_t)be * (M_ * S_);

    float4* ent_out = (float4*)(out) + (size_t)be * H4_;
    float4* men_out = (float4*)(out + MEN_OFFSET) + (size_t)be * (M_ * H4_);

    float ex = 0.f, ey = 0.f, ez = 0.f, ew = 0.f;

    #pragma unroll
    for (int m = 0; m < M_; ++m) {
        const int i0 = ip[m * S_ + 0];
        const int i1 = ip[m * S_ + 1];
        const int i2 = ip[m * S_ + 2];
        const int i3 = ip[m * S_ + 3];

        const float4 a = tb[(size_t)i0 * H4_ + t];
        const float4 c = tb[(size_t)i1 * H4_ + t];
        const float4 d = tb[(size_t)i2 * H4_ + t];
        const float4 e = tb[(size_t)i3 * H4_ + t];

        float4 mn;
        mn.x = (a.x + c.x + d.x + e.x) * 0.25f;
        mn.y = (a.y + c.y + d.y + e.y) * 0.25f;
        mn.z = (a.z + c.z + d.z + e.z) * 0.25f;
        mn.w = (a.w + c.w + d.w + e.w) * 0.25f;

        men_out[(size_t)m * H4_ + t] = mn;

        ex += mn.x; ey += mn.y; ez += mn.z; ew += mn.w;
    }

    float4 ev;
    ev.x = ex * (1.0f / M_);
    ev.y = ey * (1.0f / M_);
    ev.z = ez * (1.0f / M_);
    ev.w = ew * (1.0f / M_);
    ent_out[t] = ev;

    if (t < M_) {
        out[MASK_OFFSET + (size_t)be * M_ + t] = 1.0f;
    }
}

extern "C" void kernel_launch(void* const* d_in, const int* in_sizes, int n_in,
                              void* d_out, int out_size, void* d_ws, size_t ws_size,
                              hipStream_t stream) {
    const float* tok = (const float*)d_in[0];
    const int*   idx = (const int*)d_in[1];
    float*       out = (float*)d_out;

    dim3 grid(B_ * E_);   // 1024 blocks, one per (b, e)
    dim3 block(H4_);      // 192 threads = 3 waves, one float4 column each
    entity_repr_kernel<<<grid, block, 0, stream>>>(tok, idx, out);
}